// Round 15
// baseline (1780.991 us; speedup 1.0000x reference)
//
#include <hip/hip_runtime.h>

// GPT forward: L=4, H=4, C=1024, HS=256, V=32000, B=4, T=1024. f32 in/out.
// bf16 MFMA 16x16x32. Big GEMMs: 256x256-tile 8-wave MERGED-region pipeline
// (32 MFMA + 12 ds_read + 4 gload per region, 4 regions/128-K; counted
// vmcnt(8); st_16x32 swizzle; setprio; __launch_bounds__(512,1) so the
// ~244-VGPR working set fits without spill — LDS already caps 1 block/CU).
// LDS-transposed coalesced epilogues, NT f32 stores, QKV emits vT directly.
// bf16 residual stream. Triangular skips. 128x128 kernel for the rest.

#define C_  1024
#define T_  1024
#define HS_ 256
#define H_  4
#define L_  4
#define V_  32000
#define B_  4
#define M_  4096   // B_*T_

typedef __attribute__((ext_vector_type(8))) short  bfx8;
typedef __attribute__((ext_vector_type(4))) float  fx4;
typedef __attribute__((ext_vector_type(4))) unsigned short usx4;
typedef __attribute__((ext_vector_type(8))) unsigned short usx8;

__device__ __forceinline__ unsigned short f2bf(float f) {
  unsigned int u = __builtin_bit_cast(unsigned int, f);
  u += 0x7fffu + ((u >> 16) & 1u);          // round-to-nearest-even
  return (unsigned short)(u >> 16);
}
__device__ __forceinline__ float bf2f(unsigned short u) {
  return __builtin_bit_cast(float, ((unsigned int)u) << 16);
}

// async global->LDS, 16 B per lane. LDS dest = (wave-uniform base) + lane*16.
__device__ __forceinline__ void gload16(const unsigned short* g, unsigned short* l) {
  __builtin_amdgcn_global_load_lds(
      (const __attribute__((address_space(1))) unsigned int*)g,
      (__attribute__((address_space(3))) unsigned int*)l, 16, 0, 0);
}

// ============================ 128x128 kernel =================================
// TRI=1: A is lower-triangular in (m, k) -> clip K to m0+128.
// RES=1: res is bf16 (the residual stream x), added pre-store.
template<int BIAS, int RES, int RELU, int OUTBF, int TRI>
__global__ __launch_bounds__(256, 2) void gemm_bf16(
    const unsigned short* __restrict__ A, const unsigned short* __restrict__ Bm,
    const float* __restrict__ bias, const unsigned short* __restrict__ res,
    void* __restrict__ out,
    int M, int N, int K, int lda, int ldb, int ldc,
    long sA, long sB, long sC1, long sC2, int zShift, long rowOuter)
{
  __shared__ unsigned short As[128 * 32];
  __shared__ unsigned short Bs[128 * 32];
  const int z = blockIdx.z;
  A  += (long)z * sA;
  Bm += (long)z * sB;
  const long outOff = ((long)(z >> zShift)) * sC1 + (long)(z & ((1 << zShift) - 1)) * sC2;
  const int m0 = blockIdx.x * 128, n0 = blockIdx.y * 128;
  if (TRI) K = min(K, m0 + 128);
  const int tid = threadIdx.x;
  const int lane = tid & 63, wave = tid >> 6;
  const int wm = (wave >> 1) * 64, wn = (wave & 1) * 64;
  const int fr = lane & 15, kb = lane >> 4;
  const int sr = lane >> 2;
  const int csw = (((lane & 3) ^ ((lane >> 3) & 3)) << 3);
  const int aco = ((kb ^ ((lane >> 1) & 3)) << 3);

  fx4 acc[4][4] = {};

  for (int k0 = 0; k0 < K; k0 += 32) {
    #pragma unroll
    for (int i = 0; i < 2; ++i) {
      const int c = wave * 2 + i;
      gload16(A  + (long)(m0 + c * 16 + sr) * lda + k0 + csw, &As[c * 512]);
      gload16(Bm + (long)(n0 + c * 16 + sr) * ldb + k0 + csw, &Bs[c * 512]);
    }
    __syncthreads();
    bfx8 af[4], bf[4];
    #pragma unroll
    for (int i = 0; i < 4; ++i)
      af[i] = *reinterpret_cast<const bfx8*>(&As[(wm + i * 16 + fr) * 32 + aco]);
    #pragma unroll
    for (int j = 0; j < 4; ++j)
      bf[j] = *reinterpret_cast<const bfx8*>(&Bs[(wn + j * 16 + fr) * 32 + aco]);
    #pragma unroll
    for (int i = 0; i < 4; ++i)
      #pragma unroll
      for (int j = 0; j < 4; ++j)
        acc[i][j] = __builtin_amdgcn_mfma_f32_16x16x32_bf16(af[i], bf[j], acc[i][j], 0, 0, 0);
    __syncthreads();
  }

  const unsigned short* resp = res;
  if (RES) resp += outOff;
  const int rbase = (lane >> 4) * 4;
  #pragma unroll
  for (int j = 0; j < 4; ++j) {
    const int n = n0 + wn + j * 16 + fr;
    float bv = 0.f;
    if (BIAS) bv = bias[n];
    #pragma unroll
    for (int i = 0; i < 4; ++i) {
      #pragma unroll
      for (int r = 0; r < 4; ++r) {
        const int m = m0 + wm + i * 16 + rbase + r;
        const long off = outOff + ((long)(m >> 10)) * rowOuter + (long)(m & 1023) * ldc + n;
        float val = acc[i][j][r] + bv;
        if (RELU) val = fmaxf(val, 0.f);
        if (RES) val += bf2f(resp[((long)(m >> 10)) * rowOuter + (long)(m & 1023) * ldc + n]);
        if (OUTBF) ((unsigned short*)out)[off] = f2bf(val);
        else       ((float*)out)[off] = val;
      }
    }
  }
}

// ============================ 256x256 merged-region kernel ===================
// 512 thr = 8 waves (2M x 4N), wave tile 128x64. LDS: 4 kstep-slot-pairs
// (A @ slot*8192, B @ 32768+slot*8192, slot = kstep&3), 128 KB. Region q
// (one kstep of 32 K): {stage kstep q+4 (4 gloads); 12 ds_reads for kstep
// q+1 (alt reg set); 32 MFMA on current set; lgkmcnt(0)+schedbar; vmcnt(8);
// s_barrier}. VM8 at region q retires kstep q+2 before region q+1 reads it;
// stage of kstep q+4 targets slot q&3, freed at region q-1's barrier.
#define BAR() __builtin_amdgcn_s_barrier()
#define LGKM() { asm volatile("s_waitcnt lgkmcnt(0)" ::: "memory"); \
                 __builtin_amdgcn_sched_barrier(0); }
#define VM8()  asm volatile("s_waitcnt vmcnt(8)" ::: "memory")
#define STA(tau, kh) { const int tc = (tau) < NT ? (tau) : NT - 1; \
  const unsigned short* src = A + (long)(m0 + wave * 16 + srow) * lda + tc * 64 + (kh) * 32 + csw; \
  unsigned short* d = &S[(((tau) & 1) * 2 + (kh)) * 8192 + wave * 512]; \
  gload16(src, d); gload16(src + (long)128 * lda, d + 4096); }
#define STB(tau, kh) { const int tc = (tau) < NT ? (tau) : NT - 1; \
  const unsigned short* src = Bm + (long)(n0 + wave * 16 + srow) * ldb + tc * 64 + (kh) * 32 + csw; \
  unsigned short* d = &S[32768 + (((tau) & 1) * 2 + (kh)) * 8192 + wave * 512]; \
  gload16(src, d); gload16(src + (long)128 * ldb, d + 4096); }
#define RDA8(dst, par, kh) { _Pragma("unroll") for (int i = 0; i < 8; ++i) \
  dst[i] = *reinterpret_cast<const bfx8*>(&S[((par)*2+(kh))*8192 + (wr*128 + i*16 + fr)*32 + aco]); }
#define RDB(dst, par, kh) { _Pragma("unroll") for (int j = 0; j < 4; ++j) \
  dst[j] = *reinterpret_cast<const bfx8*>(&S[32768 + ((par)*2+(kh))*8192 + (wc*64 + j*16 + fr)*32 + aco]); }
#define MM32(afx, bfx) { __builtin_amdgcn_s_setprio(1); \
  _Pragma("unroll") for (int i = 0; i < 8; ++i) { _Pragma("unroll") for (int j = 0; j < 4; ++j) \
    acc[i][j] = __builtin_amdgcn_mfma_f32_16x16x32_bf16(afx[i], bfx[j], acc[i][j], 0, 0, 0); } \
  __builtin_amdgcn_s_setprio(0); }

// EPI 0: out addr = outOff + m*ldc + n (linear). NT f32 stores when !OUTBF.
// EPI 1: QKV: sel 0/1 coalesced t-major into out; sel 2 writes vT (out2)
//        directly (d-major, transposed through LDS).
// TRI 1: scores tile fully masked when by < bx -> early out.
template<int BIAS, int RELU, int OUTBF, int EPI, int TRI>
__global__ __launch_bounds__(512, 1) void gemm256(
    const unsigned short* __restrict__ A, const unsigned short* __restrict__ Bm,
    const float* __restrict__ bias, void* __restrict__ out,
    void* __restrict__ out2,
    int K, int lda, int ldb, int ldc, long sA, long sB, long sC1)
{
  __shared__ unsigned short S[65536];   // 128 KB -> 1 block/CU regardless
  if (TRI && blockIdx.y < blockIdx.x) return;   // fully-masked score tile
  const int z = blockIdx.z;
  A  += (long)z * sA;
  Bm += (long)z * sB;
  const long outOff = (long)z * sC1;
  const int m0 = blockIdx.x * 256, n0 = blockIdx.y * 256;
  const int tid = threadIdx.x;
  const int lane = tid & 63, wave = tid >> 6;
  const int wr = wave >> 2, wc = wave & 3;
  const int fr = lane & 15, kb = lane >> 4;
  const int srow = lane >> 2;
  // st_16x32: 16B slot-in-row ^= ((row&15)>>3)<<1. Pre-swizzled global source.
  const int csw = (((lane & 3) ^ (((lane >> 5) & 1) << 1)) << 3);
  const int aco = ((kb ^ (((fr >> 3) & 1) << 1)) << 3);
  const int NT = K >> 6;    // K-tiles of 64
  const int NK4 = K >> 7;   // iterations of 4 merged regions (K mult of 128)

  fx4 acc[8][4] = {};
  bfx8 afa[8], afb[8], bfa[4], bfb[4];

  // prologue: stage ksteps 0..3 (16 gloads); VM8 retires ksteps 0,1.
  STB(0, 0); STA(0, 0); STB(0, 1); STA(0, 1);
  STB(1, 0); STA(1, 0); STB(1, 1); STA(1, 1);
  VM8(); BAR();
  RDA8(afa, 0, 0); RDB(bfa, 0, 0);   // regs for kstep 0
  LGKM(); BAR();

  for (int t = 0; t < NK4; ++t) {
    const int u = 2 * t;
    // q%4==0: compute kstep (u,0) | read (u,1) | stage (u+2,0)
    STA(u + 2, 0); STB(u + 2, 0); RDA8(afb, 0, 1); RDB(bfb, 0, 1);
    MM32(afa, bfa); LGKM(); VM8(); BAR();
    // q%4==1: compute (u,1) | read (u+1,0) | stage (u+2,1)
    STA(u + 2, 1); STB(u + 2, 1); RDA8(afa, 1, 0); RDB(bfa, 1, 0);
    MM32(afb, bfb); LGKM(); VM8(); BAR();
    // q%4==2: compute (u+1,0) | read (u+1,1) | stage (u+3,0)
    STA(u + 3, 0); STB(u + 3, 0); RDA8(afb, 1, 1); RDB(bfb, 1, 1);
    MM32(afa, bfa); LGKM(); VM8(); BAR();
    // q%4==3: compute (u+1,1) | read (u+2,0) | stage (u+3,1)
    STA(u + 3, 1); STB(u + 3, 1); RDA8(afa, 0, 0); RDB(bfa, 0, 0);
    MM32(afb, bfb); LGKM(); VM8(); BAR();
  }
  asm volatile("s_waitcnt vmcnt(0)" ::: "memory");  // drain dangling prefetches
  BAR();   // no in-flight gload may write S while epilogue reuses it

  const int rbase = (lane >> 4) * 4;
  float* lf = (float*)S;

  if (EPI == 1 && (n0 >> 10) == 2) {
    // ---- v-block: write vT (b,h,d,t) directly, transposed through LDS ----
    const int h = (n0 >> 8) & 3;
    const int bq = m0 >> 10, tq0 = m0 & 1023;
    unsigned short* dstT = (unsigned short*)out2
        + ((long)bq * H_ + h) * HS_ * T_ + (long)(wc * 64) * T_ + tq0 + wr * 128;
    #pragma unroll
    for (int jh = 0; jh < 2; ++jh) {
      #pragma unroll
      for (int jj = 0; jj < 2; ++jj)
        #pragma unroll
        for (int i = 0; i < 8; ++i)
          #pragma unroll
          for (int r = 0; r < 4; ++r) {
            const int row = i * 16 + rbase + r;
            const int dL = jj * 16 + fr;
            lf[wave * 4096 + dL * 128 + (row ^ ((dL & 7) << 2))] = acc[i][jh * 2 + jj][r];
          }
      const int dl = lane & 31, th = lane >> 5;
      const int xw = (dl & 7) << 2;
      #pragma unroll
      for (int it = 0; it < 8; ++it) {
        const int t0 = th * 64 + it * 8;
        fx4 a = *reinterpret_cast<const fx4*>(&lf[wave * 4096 + dl * 128 + (t0 ^ xw)]);
        fx4 b = *reinterpret_cast<const fx4*>(&lf[wave * 4096 + dl * 128 + ((t0 + 4) ^ xw)]);
        usx8 o = { f2bf(a[0]), f2bf(a[1]), f2bf(a[2]), f2bf(a[3]),
                   f2bf(b[0]), f2bf(b[1]), f2bf(b[2]), f2bf(b[3]) };
        *reinterpret_cast<usx8*>(dstT + (long)(jh * 32 + dl) * T_ + t0) = o;
      }
      __builtin_amdgcn_sched_barrier(0);  // keep jh=1 stores after jh=0 reads
    }
    return;
  }

  // ---- LDS-transposed coalesced epilogue (general) ----
  unsigned short* dst1 = nullptr;
  if (EPI == 1) {
    const int sel = n0 >> 10, h = (n0 >> 8) & 3;
    const int bq = m0 >> 10, tq0 = m0 & 1023;
    dst1 = (unsigned short*)out + ((long)sel * B_ + bq) * H_ * T_ * HS_
         + (long)h * T_ * HS_ + (long)tq0 * HS_;
  }
  #pragma unroll
  for (int jh = 0; jh < 2; ++jh) {
    #pragma unroll
    for (int jj = 0; jj < 2; ++jj)
      #pragma unroll
      for (int i = 0; i < 8; ++i)
        #pragma unroll
        for (int r = 0; r < 4; ++r) {
          const int row = i * 16 + rbase + r;
          const int cw = (jj * 16 + fr) ^ ((row & 7) << 2);
          lf[wave * 4096 + row * 32 + cw] = acc[i][jh * 2 + jj][r];
        }
    #pragma unroll
    for (int rs = 0; rs < 16; ++rs) {
      const int row = rs * 8 + (lane >> 3);
      const int c0 = (lane & 7) * 4;
      const int cw = c0 ^ ((row & 7) << 2);
      fx4 val = *reinterpret_cast<const fx4*>(&lf[wave * 4096 + row * 32 + cw]);
      const int nl = wc * 64 + jh * 32 + c0;           // n - n0
      if (BIAS) {
        const float4 bb = *reinterpret_cast<const float4*>(bias + n0 + nl);
        val[0] += bb.x; val[1] += bb.y; val[2] += bb.z; val[3] += bb.w;
      }
      if (RELU) {
        val[0] = fmaxf(val[0], 0.f); val[1] = fmaxf(val[1], 0.f);
        val[2] = fmaxf(val[2], 0.f); val[3] = fmaxf(val[3], 0.f);
      }
      if (EPI == 1) {
        const long off = (long)(wr * 128 + row) * HS_ + nl;
        usx4 o = { f2bf(val[0]), f2bf(val[1]), f2bf(val[2]), f2bf(val[3]) };
        *reinterpret_cast<usx4*>(dst1 + off) = o;
      } else {
        const long off = outOff + (long)(m0 + wr * 128 + row) * ldc + n0 + nl;
        if (OUTBF) {
          usx4 o = { f2bf(val[0]), f2bf(val[1]), f2bf(val[2]), f2bf(val[3]) };
          *reinterpret_cast<usx4*>((unsigned short*)out + off) = o;
        } else {
          __builtin_nontemporal_store(val, reinterpret_cast<fx4*>((float*)out + off));
        }
      }
    }
    __builtin_amdgcn_sched_barrier(0);  // keep jh=1 writes after jh=0 reads
  }
}

// Tiled transpose + convert-to-bf16. src: (batch zb, R, Cc) TIN;
// dst base: dst + (zb>>zShiftT)*sOuter + (zb&mask)*(R*Cc); writes (Cc,R) bf16.
template<typename TIN>
__global__ __launch_bounds__(256) void transpose_k(const TIN* __restrict__ src,
    unsigned short* __restrict__ dst, int R, int Cc, int zShiftT, long sOuter) {
  __shared__ float ts[64][65];
  const long zb = blockIdx.z;
  src += zb * (long)R * Cc;
  dst += (zb >> zShiftT) * sOuter + (zb & ((1 << zShiftT) - 1)) * ((long)R * Cc);
  const int r0 = blockIdx.y * 64, c0 = blockIdx.x * 64;
  const int tr = threadIdx.x >> 4;
  const int tc = (threadIdx.x & 15) * 4;
  #pragma unroll
  for (int it = 0; it < 4; ++it) {
    const int r = tr + it * 16;
    float4 v;
    if constexpr (sizeof(TIN) == 4) {
      v = *reinterpret_cast<const float4*>(src + (long)(r0 + r) * Cc + c0 + tc);
    } else {
      usx4 u = *reinterpret_cast<const usx4*>(src + (long)(r0 + r) * Cc + c0 + tc);
      v.x = bf2f(u[0]); v.y = bf2f(u[1]); v.z = bf2f(u[2]); v.w = bf2f(u[3]);
    }
    ts[r][tc + 0] = v.x; ts[r][tc + 1] = v.y; ts[r][tc + 2] = v.z; ts[r][tc + 3] = v.w;
  }
  __syncthreads();
  #pragma unroll
  for (int it = 0; it < 4; ++it) {
    const int cj = tr + it * 16;
    usx4 o = { f2bf(ts[tc + 0][cj]), f2bf(ts[tc + 1][cj]),
               f2bf(ts[tc + 2][cj]), f2bf(ts[tc + 3][cj]) };
    *reinterpret_cast<usx4*>(dst + (long)(c0 + cj) * R + r0 + tc) = o;
  }
}

// Embed: writes bf16 residual stream x.
__global__ __launch_bounds__(256) void embed_k(const int* __restrict__ idx,
                                               const float* __restrict__ tok,
                                               const float* __restrict__ pos,
                                               unsigned short* __restrict__ x) {
  const int row = blockIdx.x;
  const int t = row & (T_ - 1);
  const int id = idx[row];
  const int c = threadIdx.x * 4;
  const float4 a = *reinterpret_cast<const float4*>(tok + (long)id * C_ + c);
  const float4 p = *reinterpret_cast<const float4*>(pos + (long)t * C_ + c);
  usx4 ov = { f2bf(a.x + p.x), f2bf(a.y + p.y), f2bf(a.z + p.z), f2bf(a.w + p.w) };
  *reinterpret_cast<usx4*>(x + (long)row * C_ + c) = ov;
}

// LayerNorm: bf16 in, bf16 out.
__global__ __launch_bounds__(256) void ln_k(const unsigned short* __restrict__ x,
                                            const float* __restrict__ g,
                                            const float* __restrict__ b,
                                            unsigned short* __restrict__ o) {
  __shared__ float red[8];
  const int row = blockIdx.x;
  const int c = threadIdx.x * 4;
  const usx4 u = *reinterpret_cast<const usx4*>(x + (long)row * C_ + c);
  const float vx = bf2f(u[0]), vy = bf2f(u[1]), vz = bf2f(u[2]), vw = bf2f(u[3]);
  float s1 = vx + vy + vz + vw;
  float s2 = vx * vx + vy * vy + vz * vz + vw * vw;
  #pragma unroll
  for (int off = 32; off; off >>= 1) {
    s1 += __shfl_xor(s1, off, 64);
    s2 += __shfl_xor(s2, off, 64);
  }
  const int lane = threadIdx.x & 63, w = threadIdx.x >> 6;
  if (lane == 0) { red[w] = s1; red[4 + w] = s2; }
  __syncthreads();
  s1 = red[0] + red[1] + red[2] + red[3];
  s2 = red[4] + red[5] + red[6] + red[7];
  const float mu = s1 * (1.f / C_);
  float var = s2 * (1.f / C_) - mu * mu;
  var = fmaxf(var, 0.f);
  const float inv = rsqrtf(var + 1e-5f);
  const float4 gg = *reinterpret_cast<const float4*>(g + c);
  const float4 bb = *reinterpret_cast<const float4*>(b + c);
  usx4 ov;
  ov[0] = f2bf((vx - mu) * inv * gg.x + bb.x);
  ov[1] = f2bf((vy - mu) * inv * gg.y + bb.y);
  ov[2] = f2bf((vz - mu) * inv * gg.z + bb.z);
  ov[3] = f2bf((vw - mu) * inv * gg.w + bb.w);
  *reinterpret_cast<usx4*>(o + (long)row * C_ + c) = ov;
}

// Fused column-softmax + transpose. In: S^T (z, s, t) bf16. Out: alpha (z, t, s)
// bf16. Softmax over t, fixed shift m=0 (|scores/32| small; shift-invariant).
// Fully-masked t-chunks (t_max < s0) are skipped on read / written as zeros.
__global__ __launch_bounds__(256) void colsmT_k(const unsigned short* __restrict__ sc,
                                                unsigned short* __restrict__ alpha) {
  __shared__ float invs[64];
  __shared__ float tile[64][65];
  const int z = blockIdx.z;
  const int s0 = blockIdx.x * 64;
  const int r = threadIdx.x >> 2;       // 0..63 (s-local)
  const int tq = threadIdx.x & 3;       // t-quarter
  const int s = s0 + r;
  const unsigned short* p = sc + (long)z * T_ * T_ + (long)s * T_ + tq * 256;
  const float scale = 0.03125f;

  // pass 1: Z (masked, shift 0); skip chunks entirely below s0
  const int i0 = min(32, max(0, s0 - tq * 256) >> 3);
  float zsum = 0.f;
  for (int i = i0; i < 32; ++i) {
    const usx8 u = *reinterpret_cast<const usx8*>(p + i * 8);
    #pragma unroll
    for (int j = 0; j < 8; ++j) {
      const int t = tq * 256 + i * 8 + j;
      if (t >= s) zsum += __expf(bf2f(u[j]) * scale);
    }
  }
  zsum += __shfl_xor(zsum, 1, 64);
  zsum += __shfl_xor(zsum, 2, 64);
  if (tq == 0) invs[r] = 1.f / zsum;
  __syncthreads();
  const float inv = invs[r];

  // pass 2: 16 t-chunks of 64; fully-masked chunks -> direct zero writes
  const unsigned short* prow = sc + (long)z * T_ * T_ + (long)s * T_;
  unsigned short* ob = alpha + (long)z * T_ * T_ + s0;
  const int wrow = threadIdx.x >> 2;    // t-local on write
  const int seg  = threadIdx.x & 3;     // s-16-segment on write
  for (int tc = 0; tc < 16; ++tc) {
    unsigned short* od = ob + (long)(tc * 64 + wrow) * T_ + seg * 16;
    if (tc * 64 + 63 < s0) {            // block-uniform: all-zero tile
      usx8 zv = {};
      *reinterpret_cast<usx8*>(od) = zv;
      *reinterpret_cast<usx8*>(od + 8) = zv;
      continue;
    }
    #pragma unroll
    for (int half = 0; half < 2; ++half) {
      const int tb = tc * 64 + tq * 16 + half * 8;
      const usx8 u = *reinterpret_cast<const usx8*>(prow + tb);
      #pragma unroll
      for (int j = 0; j < 8; ++j) {
        const int t = tb + j;
        const float a = (t >= s) ? __expf(bf2f(u[j]) * scale) * inv : 0.f;
        tile[tq * 16 + half * 8 + j][r] = a;
      }
    }
    __syncthreads();
    usx8 o0, o1;
    #pragma unroll
    for (int k = 0; k < 8; ++k) o0[k] = f2bf(tile[wrow][seg * 16 + k]);
    #pragma unroll
    for (int k = 0; k < 8; ++k) o1[k] = f2bf(tile[wrow][seg * 16 + 8 + k]);
    *reinterpret_cast<usx8*>(od) = o0;
    *reinterpret_cast<usx8*>(od + 8) = o1;
    __syncthreads();
  }
}

extern "C" void kernel_launch(void* const* d_in, const int* in_sizes, int n_in,
                              void* d_out, int out_size, void* d_ws, size_t ws_size,
                              hipStream_t stream) {
  const int*   idx    = (const int*)d_in[0];
  const float* tok    = (const float*)d_in[1];
  const float* pos    = (const float*)d_in[2];
  const float* wq     = (const float*)d_in[3];
  const float* wk     = (const float*)d_in[4];
  const float* wv     = (const float*)d_in[5];
  const float* proj_w = (const float*)d_in[6];
  const float* proj_b = (const float*)d_in[7];
  const float* ln1_g  = (const float*)d_in[8];
  const float* ln1_b  = (const float*)d_in[9];
  const float* ln2_g  = (const float*)d_in[10];
  const float* ln2_b  = (const float*)d_in[11];
  const float* ff_w1  = (const float*)d_in[12];
  const float* ff_b1  = (const float*)d_in[13];
  const float* ff_w2  = (const float*)d_in[14];
  const float* ff_b2  = (const float*)d_in[15];
  const float* lnf_g  = (const float*)d_in[16];
  const float* lnf_b  = (const float*)d_in[17];
  const float* head_w = (const float*)d_in[18];
  const float* head_b = (const float*)d_in[19];
  float* outp = (float*)d_out;

  typedef unsigned short us;
  char* w = (char*)d_ws;
  us* x       = (us*)(w + 0);               //  8 MB (M,C) bf16 residual stream
  us* xn      = (us*)(w + 16777216);        //  8 MB (M,C)
  us* qkv     = (us*)(w + 25165824);        // 24 MB: q,k (v region unused)
  us* kptr    = qkv + 4194304;
  us* vT      = (us*)(w + 50331648);        //  8 MB (B,H,HS,T)
  us* yc      = (us*)(w + 58720256);        //  8 MB (B,T,C)
  us* sc      = (us*)(w + 67108864);        // 32 MB (B*H,T,T) scores S^T
  us* headT   = (us*)(w + 67108864);        // 65.5 MB alias over sc+alpha
  us* alpha   = (us*)(w + 100663296);       // 32 MB (B*H,T,T)
  us* hidden  = (us*)(w + 134217728);       // 32 MB (M,4C)
  us* wqkvT   = (us*)(w + 167772160);       // 24 MB (L,3,H,HS,C)
  us* projT   = (us*)(w + 192937984);       //  8 MB (L,C,C)
  us* ff1T    = (us*)(w + 201326592);       // 32 MB (L,4C,C)
  us* ff2T    = (us*)(w + 234881024);       // 32 MB (L,C,4C)
  if (ws_size < (size_t)268435456) return;  // fail loudly

  const long HHC = (long)H_ * HS_ * C_;     // per-matrix per-layer us
  // ---- one-time weight transpose + bf16 convert ----
  transpose_k<float><<<dim3(HS_/64, C_/64, L_*H_), 256, 0, stream>>>(wq, wqkvT,           C_, HS_, 2, 3*HHC);
  transpose_k<float><<<dim3(HS_/64, C_/64, L_*H_), 256, 0, stream>>>(wk, wqkvT + HHC,     C_, HS_, 2, 3*HHC);
  transpose_k<float><<<dim3(HS_/64, C_/64, L_*H_), 256, 0, stream>>>(wv, wqkvT + 2*HHC,   C_, HS_, 2, 3*HHC);
  transpose_k<float><<<dim3(C_/64, C_/64, L_), 256, 0, stream>>>(proj_w, projT, C_, C_, 0, (long)C_*C_);
  transpose_k<float><<<dim3(4*C_/64, C_/64, L_), 256, 0, stream>>>(ff_w1, ff1T, C_, 4*C_, 0, (long)C_*4*C_);
  transpose_k<float><<<dim3(C_/64, 4*C_/64, L_), 256, 0, stream>>>(ff_w2, ff2T, 4*C_, C_, 0, (long)4*C_*C_);

  embed_k<<<M_, 256, 0, stream>>>(idx, tok, pos, x);

  for (int l = 0; l < L_; ++l) {
    ln_k<<<M_, 256, 0, stream>>>(x, ln1_g + l * C_, ln1_b + l * C_, xn);

    // merged QKV: N=3072; q,k -> qkv (t-major), v -> vT (d-major, direct)
    dim3 gqkv(M_/256, 3*C_/256, 1);
    gemm256<0,0,1,1,0><<<gqkv, 512, 0, stream>>>(xn, wqkvT + l * 3 * HHC, nullptr, qkv,
        vT, C_, C_, C_, 0, 0, 0, 0);

    // S^T[s][t] = sum_d K[s,d]*Q[t,d]  -> bf16; fully-masked tiles early-exit
    dim3 gs(T_/256, T_/256, B_*H_);
    gemm256<0,0,1,0,1><<<gs, 512, 0, stream>>>(kptr, qkv, nullptr, sc,
        nullptr, HS_, HS_, HS_, T_, (long)T_*HS_, (long)T_*HS_, (long)T_*T_);

    // fused softmax-over-t + transpose -> alpha (z, t, s)
    colsmT_k<<<dim3(T_/64, 1, B_*H_), 256, 0, stream>>>(sc, alpha);

    // y[t,d] = sum_s alpha[t,s]*vT[d,s]; alpha lower-triangular -> K clipped
    dim3 gp(T_/128, HS_/128, B_*H_);
    gemm_bf16<0,0,0,1,1><<<gp, 256, 0, stream>>>(alpha, vT, nullptr, nullptr, yc,
        T_, HS_, T_, T_, T_, C_, (long)T_*T_, (long)HS_*T_, (long)T_*C_, HS_, 2, (long)T_*C_);

    // x = x + yc @ proj_w + proj_b   (bf16 residual out)
    dim3 gj(M_/128, C_/128, 1);
    gemm_bf16<1,1,0,1,0><<<gj, 256, 0, stream>>>(yc, projT + (long)l*C_*C_, proj_b + l*C_, x, x,
        M_, C_, C_, C_, C_, C_, 0, 0, 0, 0, 0, (long)T_*C_);

    ln_k<<<M_, 256, 0, stream>>>(x, ln2_g + l * C_, ln2_b + l * C_, xn);

    // hidden = relu(xn @ ff_w1 + b1)  bf16
    dim3 g1(M_/256, 4*C_/256, 1);
    gemm256<1,1,1,0,0><<<g1, 512, 0, stream>>>(xn, ff1T + (long)l*4*C_*C_, ff_b1 + (long)l*4*C_,
        hidden, nullptr, C_, C_, C_, 4*C_, 0, 0, 0);

    // x = x + hidden @ ff_w2 + b2   (bf16 residual out)
    dim3 g2(M_/128, C_/128, 1);
    gemm_bf16<1,1,0,1,0><<<g2, 256, 0, stream>>>(hidden, ff2T + (long)l*C_*4*C_, ff_b2 + l*C_, x, x,
        M_, C_, 4*C_, 4*C_, 4*C_, C_, 0, 0, 0, 0, 0, (long)T_*C_);
  }

  ln_k<<<M_, 256, 0, stream>>>(x, lnf_g, lnf_b, xn);

  // head weight transpose into the (now dead) scores/alpha region
  transpose_k<float><<<dim3(V_/64, C_/64, 1), 256, 0, stream>>>(head_w, headT, C_, V_, 0, (long)C_*V_);

  dim3 gh(M_/256, V_/256, 1);
  gemm256<1,0,0,0,0><<<gh, 512, 0, stream>>>(xn, headT, head_b, outp,
      nullptr, C_, C_, C_, V_, 0, 0, 0);
}

// Round 16
// 1480.232 us; speedup vs baseline: 1.2032x; 1.2032x over previous
//
#include <hip/hip_runtime.h>

// GPT forward: L=4, H=4, C=1024, HS=256, V=32000, B=4, T=1024. f32 in/out.
// bf16 MFMA 16x16x32. Big GEMMs: 256x256-tile 8-wave pipelined kernel
// (round-9 schedule; counted vmcnt(8), st_16x32 swizzle, setprio, LDS-
// transposed coalesced epilogue, NT f32 stores; QKV epilogue emits vT
// directly). Residual stream x kept in bf16. Triangular skips: scores
// early-exit, PV K-clip, colsmT chunk skip. 128x128 kernel for the rest.
// NOTE: merged-region schedule (32 MFMA/region) spills at this register
// budget (tested twice: VGPR capped at 128 + scratch) — do not retry.

#define C_  1024
#define T_  1024
#define HS_ 256
#define H_  4
#define L_  4
#define V_  32000
#define B_  4
#define M_  4096   // B_*T_

typedef __attribute__((ext_vector_type(8))) short  bfx8;
typedef __attribute__((ext_vector_type(4))) float  fx4;
typedef __attribute__((ext_vector_type(4))) unsigned short usx4;
typedef __attribute__((ext_vector_type(8))) unsigned short usx8;

__device__ __forceinline__ unsigned short f2bf(float f) {
  unsigned int u = __builtin_bit_cast(unsigned int, f);
  u += 0x7fffu + ((u >> 16) & 1u);          // round-to-nearest-even
  return (unsigned short)(u >> 16);
}
__device__ __forceinline__ float bf2f(unsigned short u) {
  return __builtin_bit_cast(float, ((unsigned int)u) << 16);
}

// async global->LDS, 16 B per lane. LDS dest = (wave-uniform base) + lane*16.
__device__ __forceinline__ void gload16(const unsigned short* g, unsigned short* l) {
  __builtin_amdgcn_global_load_lds(
      (const __attribute__((address_space(1))) unsigned int*)g,
      (__attribute__((address_space(3))) unsigned int*)l, 16, 0, 0);
}

// ============================ 128x128 kernel =================================
// TRI=1: A is lower-triangular in (m, k) -> clip K to m0+128.
// RES=1: res is bf16 (the residual stream x), added pre-store.
template<int BIAS, int RES, int RELU, int OUTBF, int TRI>
__global__ __launch_bounds__(256, 2) void gemm_bf16(
    const unsigned short* __restrict__ A, const unsigned short* __restrict__ Bm,
    const float* __restrict__ bias, const unsigned short* __restrict__ res,
    void* __restrict__ out,
    int M, int N, int K, int lda, int ldb, int ldc,
    long sA, long sB, long sC1, long sC2, int zShift, long rowOuter)
{
  __shared__ unsigned short As[128 * 32];
  __shared__ unsigned short Bs[128 * 32];
  const int z = blockIdx.z;
  A  += (long)z * sA;
  Bm += (long)z * sB;
  const long outOff = ((long)(z >> zShift)) * sC1 + (long)(z & ((1 << zShift) - 1)) * sC2;
  const int m0 = blockIdx.x * 128, n0 = blockIdx.y * 128;
  if (TRI) K = min(K, m0 + 128);
  const int tid = threadIdx.x;
  const int lane = tid & 63, wave = tid >> 6;
  const int wm = (wave >> 1) * 64, wn = (wave & 1) * 64;
  const int fr = lane & 15, kb = lane >> 4;
  const int sr = lane >> 2;
  const int csw = (((lane & 3) ^ ((lane >> 3) & 3)) << 3);
  const int aco = ((kb ^ ((lane >> 1) & 3)) << 3);

  fx4 acc[4][4] = {};

  for (int k0 = 0; k0 < K; k0 += 32) {
    #pragma unroll
    for (int i = 0; i < 2; ++i) {
      const int c = wave * 2 + i;
      gload16(A  + (long)(m0 + c * 16 + sr) * lda + k0 + csw, &As[c * 512]);
      gload16(Bm + (long)(n0 + c * 16 + sr) * ldb + k0 + csw, &Bs[c * 512]);
    }
    __syncthreads();
    bfx8 af[4], bf[4];
    #pragma unroll
    for (int i = 0; i < 4; ++i)
      af[i] = *reinterpret_cast<const bfx8*>(&As[(wm + i * 16 + fr) * 32 + aco]);
    #pragma unroll
    for (int j = 0; j < 4; ++j)
      bf[j] = *reinterpret_cast<const bfx8*>(&Bs[(wn + j * 16 + fr) * 32 + aco]);
    #pragma unroll
    for (int i = 0; i < 4; ++i)
      #pragma unroll
      for (int j = 0; j < 4; ++j)
        acc[i][j] = __builtin_amdgcn_mfma_f32_16x16x32_bf16(af[i], bf[j], acc[i][j], 0, 0, 0);
    __syncthreads();
  }

  const unsigned short* resp = res;
  if (RES) resp += outOff;
  const int rbase = (lane >> 4) * 4;
  #pragma unroll
  for (int j = 0; j < 4; ++j) {
    const int n = n0 + wn + j * 16 + fr;
    float bv = 0.f;
    if (BIAS) bv = bias[n];
    #pragma unroll
    for (int i = 0; i < 4; ++i) {
      #pragma unroll
      for (int r = 0; r < 4; ++r) {
        const int m = m0 + wm + i * 16 + rbase + r;
        const long off = outOff + ((long)(m >> 10)) * rowOuter + (long)(m & 1023) * ldc + n;
        float val = acc[i][j][r] + bv;
        if (RELU) val = fmaxf(val, 0.f);
        if (RES) val += bf2f(resp[((long)(m >> 10)) * rowOuter + (long)(m & 1023) * ldc + n]);
        if (OUTBF) ((unsigned short*)out)[off] = f2bf(val);
        else       ((float*)out)[off] = val;
      }
    }
  }
}

// ============================ 256x256 pipelined kernel =======================
// Round-9 structure (VGPR ~124): 512 thr = 8 waves (2M x 4N), wave tile
// 128x64, BK=64 (2 ksteps of 32). LDS: 8 slots [256 rows][32 K] bf16.
// Region q: {stage 1 half-tile; ds_reads for region q+1 (alt reg set);
// 16 MFMA on current set; lgkmcnt(0)+schedbar; [even q] vmcnt(8); s_barrier}.
#define BAR() __builtin_amdgcn_s_barrier()
#define LGKM() { asm volatile("s_waitcnt lgkmcnt(0)" ::: "memory"); \
                 __builtin_amdgcn_sched_barrier(0); }
#define VM8()  asm volatile("s_waitcnt vmcnt(8)" ::: "memory")
#define STA(tau, kh) { const int tc = (tau) < NT ? (tau) : NT - 1; \
  const unsigned short* src = A + (long)(m0 + wave * 16 + srow) * lda + tc * 64 + (kh) * 32 + csw; \
  unsigned short* d = &S[(((tau) & 1) * 2 + (kh)) * 8192 + wave * 512]; \
  gload16(src, d); gload16(src + (long)128 * lda, d + 4096); }
#define STB(tau, kh) { const int tc = (tau) < NT ? (tau) : NT - 1; \
  const unsigned short* src = Bm + (long)(n0 + wave * 16 + srow) * ldb + tc * 64 + (kh) * 32 + csw; \
  unsigned short* d = &S[32768 + (((tau) & 1) * 2 + (kh)) * 8192 + wave * 512]; \
  gload16(src, d); gload16(src + (long)128 * ldb, d + 4096); }
#define RDA(dst, par, kh, rh) { _Pragma("unroll") for (int i = 0; i < 4; ++i) \
  dst[i] = *reinterpret_cast<const bfx8*>(&S[((par)*2+(kh))*8192 + (wr*128 + (rh)*64 + i*16 + fr)*32 + aco]); }
#define RDB(dst, par, kh) { _Pragma("unroll") for (int j = 0; j < 4; ++j) \
  dst[j] = *reinterpret_cast<const bfx8*>(&S[32768 + ((par)*2+(kh))*8192 + (wc*64 + j*16 + fr)*32 + aco]); }
#define MM(rh, afx, bfx) { __builtin_amdgcn_s_setprio(1); \
  _Pragma("unroll") for (int i = 0; i < 4; ++i) { _Pragma("unroll") for (int j = 0; j < 4; ++j) \
    acc[(rh)*4+i][j] = __builtin_amdgcn_mfma_f32_16x16x32_bf16(afx[i], bfx[j], acc[(rh)*4+i][j], 0, 0, 0); } \
  __builtin_amdgcn_s_setprio(0); }

// EPI 0: out addr = outOff + m*ldc + n (linear). NT f32 stores when !OUTBF.
// EPI 1: QKV: sel 0/1 coalesced t-major into out; sel 2 writes vT (out2)
//        directly (d-major, transposed through LDS).
// TRI 1: scores tile fully masked when by < bx -> early out.
template<int BIAS, int RELU, int OUTBF, int EPI, int TRI>
__global__ __launch_bounds__(512, 2) void gemm256(
    const unsigned short* __restrict__ A, const unsigned short* __restrict__ Bm,
    const float* __restrict__ bias, void* __restrict__ out,
    void* __restrict__ out2,
    int K, int lda, int ldb, int ldc, long sA, long sB, long sC1)
{
  __shared__ unsigned short S[65536];   // 128 KB
  if (TRI && blockIdx.y < blockIdx.x) return;   // fully-masked score tile
  const int z = blockIdx.z;
  A  += (long)z * sA;
  Bm += (long)z * sB;
  const long outOff = (long)z * sC1;
  const int m0 = blockIdx.x * 256, n0 = blockIdx.y * 256;
  const int tid = threadIdx.x;
  const int lane = tid & 63, wave = tid >> 6;
  const int wr = wave >> 2, wc = wave & 3;
  const int fr = lane & 15, kb = lane >> 4;
  const int srow = lane >> 2;
  // st_16x32: 16B slot-in-row ^= ((row&15)>>3)<<1. Pre-swizzled global source.
  const int csw = (((lane & 3) ^ (((lane >> 5) & 1) << 1)) << 3);
  const int aco = ((kb ^ (((fr >> 3) & 1) << 1)) << 3);
  const int NT = K >> 6;    // K-tiles of 64 (NT even for all our shapes)
  const int NI = NT >> 1;

  fx4 acc[8][4] = {};
  bfx8 afa[4], afb[4], bf0[4], bf1[4];

  // prologue: stage ktiles 0,1 fully (8 half-tiles, consumption order)
  STB(0, 0); STA(0, 0); STB(0, 1); STA(0, 1);
  STB(1, 0); STA(1, 0); STB(1, 1); STA(1, 1);
  VM8();                      // oldest 8 done: (0,0)+(0,1) A&B landed
  BAR();
  RDA(afa, 0, 0, 0); RDB(bf1, 0, 0);   // regs for region r1's MFMA
  LGKM();
  BAR();

  for (int t = 0; t < NI; ++t) {
    const int u = 2 * t;
    STB(u + 2, 0); RDA(afb, 0, 0, 1);                 MM(0, afa, bf1); LGKM(); BAR();
    STA(u + 2, 0); RDA(afa, 0, 1, 0); RDB(bf0, 0, 1); MM(1, afb, bf1); LGKM(); VM8(); BAR();
    STB(u + 2, 1); RDA(afb, 0, 1, 1);                 MM(0, afa, bf0); LGKM(); BAR();
    STA(u + 2, 1); RDA(afa, 1, 0, 0); RDB(bf1, 1, 0); MM(1, afb, bf0); LGKM(); VM8(); BAR();
    STB(u + 3, 0); RDA(afb, 1, 0, 1);                 MM(0, afa, bf1); LGKM(); BAR();
    STA(u + 3, 0); RDA(afa, 1, 1, 0); RDB(bf0, 1, 1); MM(1, afb, bf1); LGKM(); VM8(); BAR();
    STB(u + 3, 1); RDA(afb, 1, 1, 1);                 MM(0, afa, bf0); LGKM(); BAR();
    STA(u + 3, 1); RDA(afa, 0, 0, 0); RDB(bf1, 0, 0); MM(1, afb, bf0); LGKM(); VM8(); BAR();
  }
  asm volatile("s_waitcnt vmcnt(0)" ::: "memory");  // drain dangling prefetches
  BAR();   // no in-flight gload may write S while epilogue reuses it

  const int rbase = (lane >> 4) * 4;
  float* lf = (float*)S;

  if (EPI == 1 && (n0 >> 10) == 2) {
    // ---- v-block: write vT (b,h,d,t) directly, transposed through LDS ----
    const int h = (n0 >> 8) & 3;
    const int bq = m0 >> 10, tq0 = m0 & 1023;
    unsigned short* dstT = (unsigned short*)out2
        + ((long)bq * H_ + h) * HS_ * T_ + (long)(wc * 64) * T_ + tq0 + wr * 128;
    #pragma unroll
    for (int jh = 0; jh < 2; ++jh) {
      #pragma unroll
      for (int jj = 0; jj < 2; ++jj)
        #pragma unroll
        for (int i = 0; i < 8; ++i)
          #pragma unroll
          for (int r = 0; r < 4; ++r) {
            const int row = i * 16 + rbase + r;
            const int dL = jj * 16 + fr;
            lf[wave * 4096 + dL * 128 + (row ^ ((dL & 7) << 2))] = acc[i][jh * 2 + jj][r];
          }
      const int dl = lane & 31, th = lane >> 5;
      const int xw = (dl & 7) << 2;
      #pragma unroll
      for (int it = 0; it < 8; ++it) {
        const int t0 = th * 64 + it * 8;
        fx4 a = *reinterpret_cast<const fx4*>(&lf[wave * 4096 + dl * 128 + (t0 ^ xw)]);
        fx4 b = *reinterpret_cast<const fx4*>(&lf[wave * 4096 + dl * 128 + ((t0 + 4) ^ xw)]);
        usx8 o = { f2bf(a[0]), f2bf(a[1]), f2bf(a[2]), f2bf(a[3]),
                   f2bf(b[0]), f2bf(b[1]), f2bf(b[2]), f2bf(b[3]) };
        *reinterpret_cast<usx8*>(dstT + (long)(jh * 32 + dl) * T_ + t0) = o;
      }
      __builtin_amdgcn_sched_barrier(0);  // keep jh=1 stores after jh=0 reads
    }
    return;
  }

  // ---- LDS-transposed coalesced epilogue (general) ----
  unsigned short* dst1 = nullptr;
  if (EPI == 1) {
    const int sel = n0 >> 10, h = (n0 >> 8) & 3;
    const int bq = m0 >> 10, tq0 = m0 & 1023;
    dst1 = (unsigned short*)out + ((long)sel * B_ + bq) * H_ * T_ * HS_
         + (long)h * T_ * HS_ + (long)tq0 * HS_;
  }
  #pragma unroll
  for (int jh = 0; jh < 2; ++jh) {
    #pragma unroll
    for (int jj = 0; jj < 2; ++jj)
      #pragma unroll
      for (int i = 0; i < 8; ++i)
        #pragma unroll
        for (int r = 0; r < 4; ++r) {
          const int row = i * 16 + rbase + r;
          const int cw = (jj * 16 + fr) ^ ((row & 7) << 2);
          lf[wave * 4096 + row * 32 + cw] = acc[i][jh * 2 + jj][r];
        }
    #pragma unroll
    for (int rs = 0; rs < 16; ++rs) {
      const int row = rs * 8 + (lane >> 3);
      const int c0 = (lane & 7) * 4;
      const int cw = c0 ^ ((row & 7) << 2);
      fx4 val = *reinterpret_cast<const fx4*>(&lf[wave * 4096 + row * 32 + cw]);
      const int nl = wc * 64 + jh * 32 + c0;           // n - n0
      if (BIAS) {
        const float4 bb = *reinterpret_cast<const float4*>(bias + n0 + nl);
        val[0] += bb.x; val[1] += bb.y; val[2] += bb.z; val[3] += bb.w;
      }
      if (RELU) {
        val[0] = fmaxf(val[0], 0.f); val[1] = fmaxf(val[1], 0.f);
        val[2] = fmaxf(val[2], 0.f); val[3] = fmaxf(val[3], 0.f);
      }
      if (EPI == 1) {
        const long off = (long)(wr * 128 + row) * HS_ + nl;
        usx4 o = { f2bf(val[0]), f2bf(val[1]), f2bf(val[2]), f2bf(val[3]) };
        *reinterpret_cast<usx4*>(dst1 + off) = o;
      } else {
        const long off = outOff + (long)(m0 + wr * 128 + row) * ldc + n0 + nl;
        if (OUTBF) {
          usx4 o = { f2bf(val[0]), f2bf(val[1]), f2bf(val[2]), f2bf(val[3]) };
          *reinterpret_cast<usx4*>((unsigned short*)out + off) = o;
        } else {
          __builtin_nontemporal_store(val, reinterpret_cast<fx4*>((float*)out + off));
        }
      }
    }
    __builtin_amdgcn_sched_barrier(0);  // keep jh=1 writes after jh=0 reads
  }
}

// Tiled transpose + convert-to-bf16. src: (batch zb, R, Cc) TIN;
// dst base: dst + (zb>>zShiftT)*sOuter + (zb&mask)*(R*Cc); writes (Cc,R) bf16.
template<typename TIN>
__global__ __launch_bounds__(256) void transpose_k(const TIN* __restrict__ src,
    unsigned short* __restrict__ dst, int R, int Cc, int zShiftT, long sOuter) {
  __shared__ float ts[64][65];
  const long zb = blockIdx.z;
  src += zb * (long)R * Cc;
  dst += (zb >> zShiftT) * sOuter + (zb & ((1 << zShiftT) - 1)) * ((long)R * Cc);
  const int r0 = blockIdx.y * 64, c0 = blockIdx.x * 64;
  const int tr = threadIdx.x >> 4;
  const int tc = (threadIdx.x & 15) * 4;
  #pragma unroll
  for (int it = 0; it < 4; ++it) {
    const int r = tr + it * 16;
    float4 v;
    if constexpr (sizeof(TIN) == 4) {
      v = *reinterpret_cast<const float4*>(src + (long)(r0 + r) * Cc + c0 + tc);
    } else {
      usx4 u = *reinterpret_cast<const usx4*>(src + (long)(r0 + r) * Cc + c0 + tc);
      v.x = bf2f(u[0]); v.y = bf2f(u[1]); v.z = bf2f(u[2]); v.w = bf2f(u[3]);
    }
    ts[r][tc + 0] = v.x; ts[r][tc + 1] = v.y; ts[r][tc + 2] = v.z; ts[r][tc + 3] = v.w;
  }
  __syncthreads();
  #pragma unroll
  for (int it = 0; it < 4; ++it) {
    const int cj = tr + it * 16;
    usx4 o = { f2bf(ts[tc + 0][cj]), f2bf(ts[tc + 1][cj]),
               f2bf(ts[tc + 2][cj]), f2bf(ts[tc + 3][cj]) };
    *reinterpret_cast<usx4*>(dst + (long)(c0 + cj) * R + r0 + tc) = o;
  }
}

// Embed: writes bf16 residual stream x.
__global__ __launch_bounds__(256) void embed_k(const int* __restrict__ idx,
                                               const float* __restrict__ tok,
                                               const float* __restrict__ pos,
                                               unsigned short* __restrict__ x) {
  const int row = blockIdx.x;
  const int t = row & (T_ - 1);
  const int id = idx[row];
  const int c = threadIdx.x * 4;
  const float4 a = *reinterpret_cast<const float4*>(tok + (long)id * C_ + c);
  const float4 p = *reinterpret_cast<const float4*>(pos + (long)t * C_ + c);
  usx4 ov = { f2bf(a.x + p.x), f2bf(a.y + p.y), f2bf(a.z + p.z), f2bf(a.w + p.w) };
  *reinterpret_cast<usx4*>(x + (long)row * C_ + c) = ov;
}

// LayerNorm: bf16 in, bf16 out.
__global__ __launch_bounds__(256) void ln_k(const unsigned short* __restrict__ x,
                                            const float* __restrict__ g,
                                            const float* __restrict__ b,
                                            unsigned short* __restrict__ o) {
  __shared__ float red[8];
  const int row = blockIdx.x;
  const int c = threadIdx.x * 4;
  const usx4 u = *reinterpret_cast<const usx4*>(x + (long)row * C_ + c);
  const float vx = bf2f(u[0]), vy = bf2f(u[1]), vz = bf2f(u[2]), vw = bf2f(u[3]);
  float s1 = vx + vy + vz + vw;
  float s2 = vx * vx + vy * vy + vz * vz + vw * vw;
  #pragma unroll
  for (int off = 32; off; off >>= 1) {
    s1 += __shfl_xor(s1, off, 64);
    s2 += __shfl_xor(s2, off, 64);
  }
  const int lane = threadIdx.x & 63, w = threadIdx.x >> 6;
  if (lane == 0) { red[w] = s1; red[4 + w] = s2; }
  __syncthreads();
  s1 = red[0] + red[1] + red[2] + red[3];
  s2 = red[4] + red[5] + red[6] + red[7];
  const float mu = s1 * (1.f / C_);
  float var = s2 * (1.f / C_) - mu * mu;
  var = fmaxf(var, 0.f);
  const float inv = rsqrtf(var + 1e-5f);
  const float4 gg = *reinterpret_cast<const float4*>(g + c);
  const float4 bb = *reinterpret_cast<const float4*>(b + c);
  usx4 ov;
  ov[0] = f2bf((vx - mu) * inv * gg.x + bb.x);
  ov[1] = f2bf((vy - mu) * inv * gg.y + bb.y);
  ov[2] = f2bf((vz - mu) * inv * gg.z + bb.z);
  ov[3] = f2bf((vw - mu) * inv * gg.w + bb.w);
  *reinterpret_cast<usx4*>(o + (long)row * C_ + c) = ov;
}

// Fused column-softmax + transpose. In: S^T (z, s, t) bf16. Out: alpha (z, t, s)
// bf16. Softmax over t, fixed shift m=0 (|scores/32| small; shift-invariant).
// Fully-masked t-chunks (t_max < s0) are skipped on read / written as zeros.
__global__ __launch_bounds__(256) void colsmT_k(const unsigned short* __restrict__ sc,
                                                unsigned short* __restrict__ alpha) {
  __shared__ float invs[64];
  __shared__ float tile[64][65];
  const int z = blockIdx.z;
  const int s0 = blockIdx.x * 64;
  const int r = threadIdx.x >> 2;       // 0..63 (s-local)
  const int tq = threadIdx.x & 3;       // t-quarter
  const int s = s0 + r;
  const unsigned short* p = sc + (long)z * T_ * T_ + (long)s * T_ + tq * 256;
  const float scale = 0.03125f;

  // pass 1: Z (masked, shift 0); skip chunks entirely below s0
  const int i0 = min(32, max(0, s0 - tq * 256) >> 3);
  float zsum = 0.f;
  for (int i = i0; i < 32; ++i) {
    const usx8 u = *reinterpret_cast<const usx8*>(p + i * 8);
    #pragma unroll
    for (int j = 0; j < 8; ++j) {
      const int t = tq * 256 + i * 8 + j;
      if (t >= s) zsum += __expf(bf2f(u[j]) * scale);
    }
  }
  zsum += __shfl_xor(zsum, 1, 64);
  zsum += __shfl_xor(zsum, 2, 64);
  if (tq == 0) invs[r] = 1.f / zsum;
  __syncthreads();
  const float inv = invs[r];

  // pass 2: 16 t-chunks of 64; fully-masked chunks -> direct zero writes
  const unsigned short* prow = sc + (long)z * T_ * T_ + (long)s * T_;
  unsigned short* ob = alpha + (long)z * T_ * T_ + s0;
  const int wrow = threadIdx.x >> 2;    // t-local on write
  const int seg  = threadIdx.x & 3;     // s-16-segment on write
  for (int tc = 0; tc < 16; ++tc) {
    unsigned short* od = ob + (long)(tc * 64 + wrow) * T_ + seg * 16;
    if (tc * 64 + 63 < s0) {            // block-uniform: all-zero tile
      usx8 zv = {};
      *reinterpret_cast<usx8*>(od) = zv;
      *reinterpret_cast<usx8*>(od + 8) = zv;
      continue;
    }
    #pragma unroll
    for (int half = 0; half < 2; ++half) {
      const int tb = tc * 64 + tq * 16 + half * 8;
      const usx8 u = *reinterpret_cast<const usx8*>(prow + tb);
      #pragma unroll
      for (int j = 0; j < 8; ++j) {
        const int t = tb + j;
        const float a = (t >= s) ? __expf(bf2f(u[j]) * scale) * inv : 0.f;
        tile[tq * 16 + half * 8 + j][r] = a;
      }
    }
    __syncthreads();
    usx8 o0, o1;
    #pragma unroll
    for (int k = 0; k < 8; ++k) o0[k] = f2bf(tile[wrow][seg * 16 + k]);
    #pragma unroll
    for (int k = 0; k < 8; ++k) o1[k] = f2bf(tile[wrow][seg * 16 + 8 + k]);
    *reinterpret_cast<usx8*>(od) = o0;
    *reinterpret_cast<usx8*>(od + 8) = o1;
    __syncthreads();
  }
}

extern "C" void kernel_launch(void* const* d_in, const int* in_sizes, int n_in,
                              void* d_out, int out_size, void* d_ws, size_t ws_size,
                              hipStream_t stream) {
  const int*   idx    = (const int*)d_in[0];
  const float* tok    = (const float*)d_in[1];
  const float* pos    = (const float*)d_in[2];
  const float* wq     = (const float*)d_in[3];
  const float* wk     = (const float*)d_in[4];
  const float* wv     = (const float*)d_in[5];
  const float* proj_w = (const float*)d_in[6];
  const float* proj_b = (const float*)d_in[7];
  const float* ln1_g  = (const float*)d_in[8];
  const float* ln1_b  = (const float*)d_in[9];
  const float* ln2_g  = (const float*)d_in[10];
  const float* ln2_b  = (const float*)d_in[11];
  const float* ff_w1  = (const float*)d_in[12];
  const float* ff_b1  = (const float*)d_in[13];
  const float* ff_w2  = (const float*)d_in[14];
  const float* ff_b2  = (const float*)d_in[15];
  const float* lnf_g  = (const float*)d_in[16];
  const float* lnf_b  = (const float*)d_in[17];
  const float* head_w = (const float*)d_in[18];
  const float* head_b = (const float*)d_in[19];
  float* outp = (float*)d_out;

  typedef unsigned short us;
  char* w = (char*)d_ws;
  us* x       = (us*)(w + 0);               //  8 MB (M,C) bf16 residual stream
  us* xn      = (us*)(w + 16777216);        //  8 MB (M,C)
  us* qkv     = (us*)(w + 25165824);        // 24 MB: q,k (v region unused)
  us* kptr    = qkv + 4194304;
  us* vT      = (us*)(w + 50331648);        //  8 MB (B,H,HS,T)
  us* yc      = (us*)(w + 58720256);        //  8 MB (B,T,C)
  us* sc      = (us*)(w + 67108864);        // 32 MB (B*H,T,T) scores S^T
  us* headT   = (us*)(w + 67108864);        // 65.5 MB alias over sc+alpha
  us* alpha   = (us*)(w + 100663296);       // 32 MB (B*H,T,T)
  us* hidden  = (us*)(w + 134217728);       // 32 MB (M,4C)
  us* wqkvT   = (us*)(w + 167772160);       // 24 MB (L,3,H,HS,C)
  us* projT   = (us*)(w + 192937984);       //  8 MB (L,C,C)
  us* ff1T    = (us*)(w + 201326592);       // 32 MB (L,4C,C)
  us* ff2T    = (us*)(w + 234881024);       // 32 MB (L,C,4C)
  if (ws_size < (size_t)268435456) return;  // fail loudly

  const long HHC = (long)H_ * HS_ * C_;     // per-matrix per-layer us
  // ---- one-time weight transpose + bf16 convert ----
  transpose_k<float><<<dim3(HS_/64, C_/64, L_*H_), 256, 0, stream>>>(wq, wqkvT,           C_, HS_, 2, 3*HHC);
  transpose_k<float><<<dim3(HS_/64, C_/64, L_*H_), 256, 0, stream>>>(wk, wqkvT + HHC,     C_, HS_, 2, 3*HHC);
  transpose_k<float><<<dim3(HS_/64, C_/64, L_*H_), 256, 0, stream>>>(wv, wqkvT + 2*HHC,   C_, HS_, 2, 3*HHC);
  transpose_k<float><<<dim3(C_/64, C_/64, L_), 256, 0, stream>>>(proj_w, projT, C_, C_, 0, (long)C_*C_);
  transpose_k<float><<<dim3(4*C_/64, C_/64, L_), 256, 0, stream>>>(ff_w1, ff1T, C_, 4*C_, 0, (long)C_*4*C_);
  transpose_k<float><<<dim3(C_/64, 4*C_/64, L_), 256, 0, stream>>>(ff_w2, ff2T, 4*C_, C_, 0, (long)4*C_*C_);

  embed_k<<<M_, 256, 0, stream>>>(idx, tok, pos, x);

  for (int l = 0; l < L_; ++l) {
    ln_k<<<M_, 256, 0, stream>>>(x, ln1_g + l * C_, ln1_b + l * C_, xn);

    // merged QKV: N=3072; q,k -> qkv (t-major), v -> vT (d-major, direct)
    dim3 gqkv(M_/256, 3*C_/256, 1);
    gemm256<0,0,1,1,0><<<gqkv, 512, 0, stream>>>(xn, wqkvT + l * 3 * HHC, nullptr, qkv,
        vT, C_, C_, C_, 0, 0, 0, 0);

    // S^T[s][t] = sum_d K[s,d]*Q[t,d]  -> bf16; fully-masked tiles early-exit
    dim3 gs(T_/256, T_/256, B_*H_);
    gemm256<0,0,1,0,1><<<gs, 512, 0, stream>>>(kptr, qkv, nullptr, sc,
        nullptr, HS_, HS_, HS_, T_, (long)T_*HS_, (long)T_*HS_, (long)T_*T_);

    // fused softmax-over-t + transpose -> alpha (z, t, s)
    colsmT_k<<<dim3(T_/64, 1, B_*H_), 256, 0, stream>>>(sc, alpha);

    // y[t,d] = sum_s alpha[t,s]*vT[d,s]; alpha lower-triangular -> K clipped
    dim3 gp(T_/128, HS_/128, B_*H_);
    gemm_bf16<0,0,0,1,1><<<gp, 256, 0, stream>>>(alpha, vT, nullptr, nullptr, yc,
        T_, HS_, T_, T_, T_, C_, (long)T_*T_, (long)HS_*T_, (long)T_*C_, HS_, 2, (long)T_*C_);

    // x = x + yc @ proj_w + proj_b   (bf16 residual out)
    dim3 gj(M_/128, C_/128, 1);
    gemm_bf16<1,1,0,1,0><<<gj, 256, 0, stream>>>(yc, projT + (long)l*C_*C_, proj_b + l*C_, x, x,
        M_, C_, C_, C_, C_, C_, 0, 0, 0, 0, 0, (long)T_*C_);

    ln_k<<<M_, 256, 0, stream>>>(x, ln2_g + l * C_, ln2_b + l * C_, xn);

    // hidden = relu(xn @ ff_w1 + b1)  bf16
    dim3 g1(M_/256, 4*C_/256, 1);
    gemm256<1,1,1,0,0><<<g1, 512, 0, stream>>>(xn, ff1T + (long)l*4*C_*C_, ff_b1 + (long)l*4*C_,
        hidden, nullptr, C_, C_, C_, 4*C_, 0, 0, 0);

    // x = x + hidden @ ff_w2 + b2   (bf16 residual out)
    dim3 g2(M_/128, C_/128, 1);
    gemm_bf16<1,1,0,1,0><<<g2, 256, 0, stream>>>(hidden, ff2T + (long)l*C_*4*C_, ff_b2 + l*C_, x, x,
        M_, C_, 4*C_, 4*C_, 4*C_, C_, 0, 0, 0, 0, 0, (long)T_*C_);
  }

  ln_k<<<M_, 256, 0, stream>>>(x, lnf_g, lnf_b, xn);

  // head weight transpose into the (now dead) scores/alpha region
  transpose_k<float><<<dim3(V_/64, C_/64, 1), 256, 0, stream>>>(head_w, headT, C_, V_, 0, (long)C_*V_);

  dim3 gh(M_/256, V_/256, 1);
  gemm256<1,0,0,0,0><<<gh, 512, 0, stream>>>(xn, headT, head_b, outp,
      nullptr, C_, C_, C_, V_, 0, 0, 0);
}